// Round 11
// baseline (458.385 us; speedup 1.0000x reference)
//
#include <hip/hip_runtime.h>

#define DEV __device__ __forceinline__

constexpr int NX = 64, NU = 32, NH = 32, NB = 192;

// workspace float offsets
constexpr int WS_P   = 0;                            // [NH+1][4096]; slot 0 -> flags
constexpr int WS_QI  = WS_P  + (NH + 1) * NX * NX;   // [NH][1024]  Quu^{-1}
constexpr int WS_X   = WS_QI + NH * NU * NU;         // [NH][64*32] Qxu x-major
constexpr int WS_K   = WS_X  + NH * NX * NU;         // [NH][32*64] K u-major
constexpr int WS_STG = WS_K  + NH * NU * NX;         // [4096] Qxx staging (producer only)

typedef __attribute__((ext_vector_type(8))) short bf16x8;
typedef __attribute__((ext_vector_type(4))) float f32x4;
typedef __attribute__((ext_vector_type(4))) unsigned short us4;

// producer LDS byte offsets. ALL packs 3-level bf16. Big packs row stride
// 72 el (144 B); small packs stride 40 el (80 B). TT 96 rows: G rows 0-63,
// V rows 64-95 (co-computed in Ph1).
constexpr int LVL_M2T = 96 * 72 * 2;   // 13824
constexpr int LVL_P   = 64 * 72 * 2;   //  9216
constexpr int LVL_TT  = 96 * 72 * 2;   // 13824
constexpr int LVL_XU  = 64 * 40 * 2;   //  5120
constexpr int LVL_KT  = 64 * 40 * 2;   //  5120
constexpr int LVL_QI  = 32 * 40 * 2;   //  2560
constexpr int oM2T = 0;
constexpr int oP   = oM2T + 3 * LVL_M2T;   //  41472
constexpr int oTT  = oP   + 3 * LVL_P;     //  69120
constexpr int oXU  = oTT  + 3 * LVL_TT;    // 110592
constexpr int oKT  = oXU  + 3 * LVL_XU;    // 125952
constexpr int oQI  = oKT  + 3 * LVL_KT;    // 141312
constexpr int oQUU = oQI  + 3 * LVL_QI;    // 148992 (fp32 32x36)
constexpr int SMEMB = oQUU + 32 * 36 * 4;  // 153600

DEV unsigned short bfh(float x) {
  unsigned u = __float_as_uint(x);
  return (unsigned short)((u + 0x7FFFu + ((u >> 16) & 1u)) >> 16);
}
DEV float bf2f(unsigned short h) { return __uint_as_float(((unsigned)h) << 16); }
DEV void split3(float x, unsigned short& h, unsigned short& m, unsigned short& l) {
  h = bfh(x); float r1 = x - bf2f(h);
  m = bfh(r1); float r2 = r1 - bf2f(m);
  l = bfh(r2);
}
DEV float4 ld4(const float* p) { return *reinterpret_cast<const float4*>(p); }
DEV void   st4(float* p, float4 v) { *reinterpret_cast<float4*>(p) = v; }
DEV void   st4v(float* p, f32x4 v) { *reinterpret_cast<f32x4*>(p) = v; }
DEV float  dot4(float4 a, float4 b) {
  return fmaf(a.x, b.x, fmaf(a.y, b.y, fmaf(a.z, b.z, a.w * b.w)));
}
DEV void fma4(float4& a, float s, float4 b) {
  a.x = fmaf(s, b.x, a.x); a.y = fmaf(s, b.y, a.y);
  a.z = fmaf(s, b.z, a.z); a.w = fmaf(s, b.w, a.w);
}
DEV void fma8(float* acc, float s, float4 b0, float4 b1) {
  acc[0] = fmaf(s, b0.x, acc[0]); acc[1] = fmaf(s, b0.y, acc[1]);
  acc[2] = fmaf(s, b0.z, acc[2]); acc[3] = fmaf(s, b0.w, acc[3]);
  acc[4] = fmaf(s, b1.x, acc[4]); acc[5] = fmaf(s, b1.y, acc[5]);
  acc[6] = fmaf(s, b1.z, acc[6]); acc[7] = fmaf(s, b1.w, acc[7]);
}

#define MFMA16(a, b, c) __builtin_amdgcn_mfma_f32_16x16x32_bf16(a, b, c, 0, 0, 0)

// 3-level x 3-level product (error ~2^-26): 6 MFMAs, small terms first.
DEV f32x4 prod33(const char* A, int ao, int LA, const char* B, int bo, int LB,
                 f32x4 acc) {
  const bf16x8 a0 = *(const bf16x8*)(A + ao);
  const bf16x8 a1 = *(const bf16x8*)(A + LA + ao);
  const bf16x8 a2 = *(const bf16x8*)(A + 2 * LA + ao);
  const bf16x8 b0 = *(const bf16x8*)(B + bo);
  const bf16x8 b1 = *(const bf16x8*)(B + LB + bo);
  const bf16x8 b2 = *(const bf16x8*)(B + 2 * LB + bo);
  acc = MFMA16(a1, b1, acc);
  acc = MFMA16(a2, b0, acc);
  acc = MFMA16(a0, b2, acc);
  acc = MFMA16(a1, b0, acc);
  acc = MFMA16(a0, b1, acc);
  acc = MFMA16(a0, b0, acc);
  return acc;
}
DEV void st_pack3(char* base, int lvl, int el, f32x4 v) {
  us4 h, m, l;
#pragma unroll
  for (int r = 0; r < 4; ++r) {
    unsigned short hh, mm, ll; split3(v[r], hh, mm, ll);
    h[r] = (short)hh; m[r] = (short)mm; l[r] = (short)ll;
  }
  *(us4*)(base + el * 2) = h;
  *(us4*)(base + lvl + el * 2) = m;
  *(us4*)(base + 2 * lvl + el * 2) = l;
}

// ---------------------------------------------------------------------------
// Producer (block 0, 512 threads): split-bf16 MFMA Riccati recursion.
// Ph1: G+V. Ph2: Quu+Qxu. Ph3: 2-pivot GJ || Qxx->gStage. Ph4: K -> flag.
// Ph5: P'. Normal stores + __threadfence before flag (R4/R5-validated).
// ---------------------------------------------------------------------------
DEV void producer(char* smem, const float* Ag, const float* Bg,
                  const float* Qxg, const float* Rug, const float* Qfg,
                  float* ws) {
  const int t = threadIdx.x, lane = t & 63, wv = t >> 6;
  const int l15 = lane & 15, l4 = lane >> 4;

  char* M2T = smem + oM2T;
  char* Pp  = smem + oP;
  char* TT  = smem + oTT;     // G rows 0-63, V rows 64-95
  char* XU  = smem + oXU;
  char* KT  = smem + oKT;
  char* QI  = smem + oQI;
  float* QUU = (float*)(smem + oQUU);

  float* gP   = ws + WS_P;
  float* gQI  = ws + WS_QI;
  float* gX   = ws + WS_X;
  float* gK   = ws + WS_K;
  float* gStg = ws + WS_STG;
  int* flags  = (int*)(ws + WS_P);    // [0..31] stage flags

  // ---- static packs: M2T[j][m] = (j<64 ? A[m][j] : B[m][j-64]); P=Qf; gP[32]
  for (int idx = t; idx < 96 * 64; idx += 512) {
    const int j = idx >> 6, m = idx & 63;
    const float v = (j < 64) ? Ag[m * 64 + j] : Bg[m * 32 + (j - 64)];
    unsigned short h, mi, lo; split3(v, h, mi, lo);
    const int eo = (j * 72 + m) * 2;
    *(unsigned short*)(M2T + eo) = h;
    *(unsigned short*)(M2T + LVL_M2T + eo) = mi;
    *(unsigned short*)(M2T + 2 * LVL_M2T + eo) = lo;
  }
  for (int idx = t; idx < 64 * 64; idx += 512) {
    const int r = idx >> 6, c = idx & 63;
    const float v = Qfg[idx];
    unsigned short h, mi, lo; split3(v, h, mi, lo);
    const int eo = (r * 72 + c) * 2;
    *(unsigned short*)(Pp + eo) = h;
    *(unsigned short*)(Pp + LVL_P + eo) = mi;
    *(unsigned short*)(Pp + 2 * LVL_P + eo) = lo;
    gP[32 * 4096 + idx] = v;
  }
  __syncthreads();

  for (int s = NH - 1; s >= 0; --s) {
    // ---- Ph1: [G|V] = P*[A|B] -> TT. 24 tiles, 3/wave, unrolled for ILP.
#pragma unroll
    for (int q = 0; q < 3; ++q) {
      const int tt = wv + q * 8;
      const int isV = tt >= 16;
      const int t2 = isV ? tt - 16 : tt;
      const int mT = t2 & 3;
      const int br = (isV ? 64 : 0) + (t2 >> 2) * 16;   // B-op / dest row base
      f32x4 acc = {0.f, 0.f, 0.f, 0.f};
#pragma unroll
      for (int kp = 0; kp < 2; ++kp) {
        const int ao = ((mT * 16 + l15) * 72 + kp * 32 + l4 * 8) * 2;
        const int bo = ((br + l15) * 72 + kp * 32 + l4 * 8) * 2;
        acc = prod33(Pp, ao, LVL_P, M2T, bo, LVL_M2T, acc);
      }
      st_pack3(TT, LVL_TT, (br + l15) * 72 + mT * 16 + l4 * 4, acc);
    }
    __syncthreads();

    // ---- Ph2: waves 0-3: Quu = Ru + B^T V ; waves 4-7: Qxu -> XU pack3 + gX
    if (wv < 4) {
      const int uA = wv >> 1, uB = wv & 1;
      f32x4 acc = {0.f, 0.f, 0.f, 0.f};
#pragma unroll
      for (int kp = 0; kp < 2; ++kp) {
        const int ao = ((64 + uA * 16 + l15) * 72 + kp * 32 + l4 * 8) * 2; // V
        const int bo = ((64 + uB * 16 + l15) * 72 + kp * 32 + l4 * 8) * 2; // B
        acc = prod33(TT, ao, LVL_TT, M2T, bo, LVL_M2T, acc);
      }
      const int c = uB * 16 + l15, u0 = uA * 16 + l4 * 4;  // symmetric store
      const float4 rv = ld4(Rug + c * 32 + u0);
      QUU[c * 36 + u0 + 0] = acc[0] + rv.x;
      QUU[c * 36 + u0 + 1] = acc[1] + rv.y;
      QUU[c * 36 + u0 + 2] = acc[2] + rv.z;
      QUU[c * 36 + u0 + 3] = acc[3] + rv.w;
    } else {
#pragma unroll
      for (int q = 0; q < 2; ++q) {
        const int tt = (wv - 4) * 2 + q;     // 0..7
        const int uT = tt & 1, xT = tt >> 1;
        f32x4 acc = {0.f, 0.f, 0.f, 0.f};
#pragma unroll
        for (int kp = 0; kp < 2; ++kp) {
          const int ao = ((64 + uT * 16 + l15) * 72 + kp * 32 + l4 * 8) * 2; // V
          const int bo = ((xT * 16 + l15) * 72 + kp * 32 + l4 * 8) * 2;      // A
          acc = prod33(TT, ao, LVL_TT, M2T, bo, LVL_M2T, acc);
        }
        const int x = xT * 16 + l15, u0 = uT * 16 + l4 * 4;
        st_pack3(XU, LVL_XU, x * 40 + u0, acc);
        st4v(gX + s * 2048 + x * 32 + u0, acc);
      }
    }
    __syncthreads();

    // ---- Ph3: wave 0: 2-pivot register GJ inverse ; waves 1-7: Qxx -> gStg
    if (wv == 0) {
      const int i = lane & 31, h = lane >> 5;
      float W[16];
#pragma unroll
      for (int r = 0; r < 16; ++r) W[r] = QUU[i * 36 + h * 16 + r];
#pragma unroll
      for (int q = 0; q < 16; ++q) {
        const int p0 = 2 * q, p1 = 2 * q + 1;
        const int jh = p0 >> 4, jr0 = p0 & 15, jr1 = jr0 + 1;
        const float a = __shfl(W[jr0], p0 | (jh << 5));
        const float b = __shfl(W[jr1], p0 | (jh << 5));
        const float c = __shfl(W[jr0], p1 | (jh << 5));
        const float d = __shfl(W[jr1], p1 | (jh << 5));
        const float rdet = 1.0f / fmaf(a, d, -b * c);
        const float Di00 = d * rdet, Di01 = -b * rdet;
        const float Di10 = -c * rdet, Di11 = a * rdet;
        const float f0 = __shfl(W[jr0], i | (jh << 5));
        const float f1 = __shfl(W[jr1], i | (jh << 5));
        float pr0[16], pr1[16];
#pragma unroll
        for (int r = 0; r < 16; ++r) {
          pr0[r] = __shfl(W[r], p0 | (h << 5));
          pr1[r] = __shfl(W[r], p1 | (h << 5));
        }
        const float g0 = fmaf(f0, Di00, f1 * Di10);
        const float g1 = fmaf(f0, Di01, f1 * Di11);
        float nw[16];
        if (i == p0) {
#pragma unroll
          for (int r = 0; r < 16; ++r) nw[r] = fmaf(Di00, pr0[r], Di01 * pr1[r]);
          if (h == jh) { nw[jr0] = Di00; nw[jr1] = Di01; }
        } else if (i == p1) {
#pragma unroll
          for (int r = 0; r < 16; ++r) nw[r] = fmaf(Di10, pr0[r], Di11 * pr1[r]);
          if (h == jh) { nw[jr0] = Di10; nw[jr1] = Di11; }
        } else {
#pragma unroll
          for (int r = 0; r < 16; ++r)
            nw[r] = fmaf(-g0, pr0[r], fmaf(-g1, pr1[r], W[r]));
          if (h == jh) { nw[jr0] = -g0; nw[jr1] = -g1; }
        }
#pragma unroll
        for (int r = 0; r < 16; ++r) W[r] = nw[r];
      }
#pragma unroll
      for (int q = 0; q < 4; ++q) {
        f32x4 o = {W[4 * q], W[4 * q + 1], W[4 * q + 2], W[4 * q + 3]};
        st4v(gQI + s * 1024 + i * 32 + h * 16 + 4 * q, o);
        st_pack3(QI, LVL_QI, i * 40 + h * 16 + 4 * q, o);
      }
    } else {
#pragma unroll
      for (int q = 0; q < 3; ++q) {
        const int tt = (wv - 1) + q * 7;
        if (tt < 16) {
          const int jT = tt >> 2, iT = tt & 3;
          f32x4 acc = {0.f, 0.f, 0.f, 0.f};
#pragma unroll
          for (int kp = 0; kp < 2; ++kp) {
            const int ao = ((jT * 16 + l15) * 72 + kp * 32 + l4 * 8) * 2; // G
            const int bo = ((iT * 16 + l15) * 72 + kp * 32 + l4 * 8) * 2; // A
            acc = prod33(TT, ao, LVL_TT, M2T, bo, LVL_M2T, acc);
          }
          const int c = iT * 16 + l15, j0 = jT * 16 + l4 * 4;
          const float4 qv = ld4(Qxg + c * 64 + j0);
          float4 o; o.x = acc[0] + qv.x; o.y = acc[1] + qv.y;
          o.z = acc[2] + qv.z; o.w = acc[3] + qv.w;
          st4(gStg + c * 64 + j0, o);      // producer-L2 hot
        }
      }
    }
    __syncthreads();

    // ---- Ph4: K = QI*Qxu^T, 8 tiles, 1/wave. gK normal; KT pack3.
    {
      const int mT = wv & 1, xT = wv >> 1;
      f32x4 acc = {0.f, 0.f, 0.f, 0.f};
      const int ao = ((mT * 16 + l15) * 40 + l4 * 8) * 2;
      const int bo = ((xT * 16 + l15) * 40 + l4 * 8) * 2;
      acc = prod33(QI, ao, LVL_QI, XU, bo, LVL_XU, acc);
      const int x = xT * 16 + l15, m0 = mT * 16 + l4 * 4;
#pragma unroll
      for (int r = 0; r < 4; ++r)
        gK[s * 2048 + (m0 + r) * 64 + x] = -acc[r];
      st_pack3(KT, LVL_KT, x * 40 + m0, acc);
    }
    __syncthreads();

    // publish stage s (gP[s+1] prev Ph5; gX Ph2; gQI Ph3; gK Ph4 — drained by
    // barriers; threadfence writes back dirty L2 for cross-XCD visibility)
    if (t == 0) {
      __threadfence();
      __hip_atomic_store(flags + s, 1, __ATOMIC_RELEASE, __HIP_MEMORY_SCOPE_AGENT);
    }

    // ---- Ph5: P' = Qxx - Qxu*K ; gP[s] + P pack3. Skip s=0.
    if (s > 0) {
#pragma unroll
      for (int q = 0; q < 2; ++q) {
        const int tt = wv + q * 8;
        const int iT = tt & 3, jT = tt >> 2;
        f32x4 acc = {0.f, 0.f, 0.f, 0.f};
        const int ao = ((iT * 16 + l15) * 40 + l4 * 8) * 2;
        const int bo = ((jT * 16 + l15) * 40 + l4 * 8) * 2;
        acc = prod33(XU, ao, LVL_XU, KT, bo, LVL_KT, acc);
        const int j = jT * 16 + l15, i0 = iT * 16 + l4 * 4;
        const float4 qx4 = ld4(gStg + j * 64 + i0);   // Qxx(j,i0..)=Qxx(i0..,j)
        f32x4 pv;
        pv[0] = qx4.x - acc[0]; pv[1] = qx4.y - acc[1];
        pv[2] = qx4.z - acc[2]; pv[3] = qx4.w - acc[3];
#pragma unroll
        for (int r = 0; r < 4; ++r)
          gP[s * 4096 + (i0 + r) * 64 + j] = pv[r];
        st_pack3(Pp, LVL_P, j * 72 + i0, pv);  // symmetry: pack[j][i]=P'[i][j]
      }
    }
    __syncthreads();
  }
}

// ---------------------------------------------------------------------------
// Consumer: per-batch residuals (threads 0-255) + wave-0 recursions.
// Backward: prefetch gX/gQI right after flag acquire. Forward: K row
// double-buffer prefetch. flags[0] (last) covers all gK.
// ---------------------------------------------------------------------------
DEV void consumer(float* lds, int b, const float* x0g, const float* xg,
                  const float* ug, const float* lg, const float* Ag,
                  const float* Bg, const float* Qxg, const float* Rug,
                  const float* Qfg, float* ws, float* outp) {
  const int t = threadIdx.x;
  const float* gP  = ws + WS_P;
  const float* gQI = ws + WS_QI;
  const float* gX  = ws + WS_X;
  const float* gK  = ws + WS_K;
  int* flags = (int*)(ws + WS_P);

  float* sx   = lds;            // 2112 (dead after residuals)
  float* sl   = lds + 2112;     // 2112 (dead after residuals)
  float* su   = lds + 4224;     // 1024 (dead after residuals)
  float* sAT  = lds;            // overlay, stride 68
  float* xres = lds + 5248;     // 2048
  float* lxs  = lds + 7296;     // 2048
  float* lus  = lds + 9344;     // 1024
  float* kv   = lds + 10368;    // 1024
  float* swv  = lds + 11392;    // 64
  float* sqv  = lds + 11456;    // 32
  float* sduv = lds + 11488;    // 32
  float* sdxv = lds + 11520;    // 64

  for (int idx = t; idx < (NH + 1) * NX; idx += 512) {
    const int s = idx >> 6, i = idx & 63;
    sx[idx] = xg[(s * NB + b) * NX + i];
    sl[idx] = lg[(s * NB + b) * NX + i];
  }
  for (int idx = t; idx < NH * NU; idx += 512) {
    const int s = idx >> 5, j = idx & 31;
    su[idx] = ug[(s * NB + b) * NU + j];
  }
  __syncthreads();

  if (t < 256) {
    const int s = t >> 3, i0 = (t & 7) * 8;
    float accx[8], accl[8];
#pragma unroll
    for (int ii = 0; ii < 8; ++ii) {
      accx[ii] = -sx[(s + 1) * NX + i0 + ii];
      accl[ii] = -sl[s * NX + i0 + ii];
    }
#pragma unroll 2
    for (int k0 = 0; k0 < NX; k0 += 4) {
      const float4 xv = ld4(sx + s * NX + k0);
#pragma unroll
      for (int ii = 0; ii < 8; ++ii) {
        accx[ii] += dot4(ld4(Ag + (i0 + ii) * NX + k0), xv);
        accl[ii] += dot4(ld4(Qxg + (i0 + ii) * NX + k0), xv);
      }
    }
#pragma unroll 2
    for (int k0 = 0; k0 < NU; k0 += 4) {
      const float4 uv = ld4(su + s * NU + k0);
#pragma unroll
      for (int ii = 0; ii < 8; ++ii)
        accx[ii] += dot4(ld4(Bg + (i0 + ii) * NU + k0), uv);
    }
#pragma unroll 4
    for (int k = 0; k < NX; ++k) {
      const float lv = sl[(s + 1) * NX + k];
      fma8(accl, lv, ld4(Ag + k * NX + i0), ld4(Ag + k * NX + i0 + 4));
    }
#pragma unroll
    for (int ii = 0; ii < 8; ++ii) {
      xres[s * NX + i0 + ii] = accx[ii];
      lxs[s * NX + i0 + ii] = accl[ii];
    }
  }
  if (t < 256) {
    const int s = t >> 3, j0 = (t & 7) * 4;
    float4 acc = {0, 0, 0, 0};
#pragma unroll 2
    for (int k0 = 0; k0 < NU; k0 += 4) {
      const float4 uv = ld4(su + s * NU + k0);
      acc.x += dot4(ld4(Rug + (j0 + 0) * NU + k0), uv);
      acc.y += dot4(ld4(Rug + (j0 + 1) * NU + k0), uv);
      acc.z += dot4(ld4(Rug + (j0 + 2) * NU + k0), uv);
      acc.w += dot4(ld4(Rug + (j0 + 3) * NU + k0), uv);
    }
#pragma unroll 4
    for (int k = 0; k < NX; ++k) {
      const float lv = sl[(s + 1) * NX + k];
      fma4(acc, lv, ld4(Bg + k * NU + j0));
    }
    lus[s * NU + j0 + 0] = acc.x; lus[s * NU + j0 + 1] = acc.y;
    lus[s * NU + j0 + 2] = acc.z; lus[s * NU + j0 + 3] = acc.w;
  }

  float p_i = 0.0f, dx_i = 0.0f;
  if (t < 64) {
    const int i = t;
    float acc = -sl[NH * NX + i];
#pragma unroll 4
    for (int k0 = 0; k0 < NX; k0 += 4)
      acc += dot4(ld4(Qfg + i * NX + k0), ld4(sx + NH * NX + k0));
    p_i = acc;
    dx_i = x0g[b * NX + i] - sx[i];
  }
  __syncthreads();

  for (int idx = t; idx < NX * NX / 4; idx += 512) {
    const int k = idx >> 4, i4 = (idx & 15) * 4;
    const float4 a4 = ld4(Ag + k * NX + i4);
    sAT[(i4 + 0) * 68 + k] = a4.x;
    sAT[(i4 + 1) * 68 + k] = a4.y;
    sAT[(i4 + 2) * 68 + k] = a4.z;
    sAT[(i4 + 3) * 68 + k] = a4.w;
  }
  __syncthreads();

  if (t >= 64) return;   // wave 0 continues barrier-free

  const int i = t;
  const int j = t & 31;
  const int hh = t >> 5;

  for (int s = NH - 1; s >= 0; --s) {
    // relaxed poll; single acquire on success
    while (__hip_atomic_load(flags + s, __ATOMIC_RELAXED,
                             __HIP_MEMORY_SCOPE_AGENT) == 0)
      __builtin_amdgcn_s_sleep(4);
    (void)__hip_atomic_load(flags + s, __ATOMIC_ACQUIRE,
                            __HIP_MEMORY_SCOPE_AGENT);

    // prefetch gX / gQI rows now — overlap with the w/qx/qu chain below
    float4 xpre[8];
    {
      const float* Xs = gX + s * 2048 + i * 32;
#pragma unroll
      for (int q = 0; q < 8; ++q) xpre[q] = ld4(Xs + q * 4);
    }
    float4 qipre[4];
    {
      const float* Qr = gQI + s * NU * NU + j * NU + hh * 16;
#pragma unroll
      for (int q = 0; q < 4; ++q) qipre[q] = ld4(Qr + q * 4);
    }

    const float* Pr = gP + (s + 1) * NX * NX + i * NX;
    const float* xr = xres + s * NX;
    float w = p_i;
#pragma unroll
    for (int k0 = 0; k0 < NX; k0 += 16) {
      w += dot4(ld4(Pr + k0),      ld4(xr + k0));
      w += dot4(ld4(Pr + k0 + 4),  ld4(xr + k0 + 4));
      w += dot4(ld4(Pr + k0 + 8),  ld4(xr + k0 + 8));
      w += dot4(ld4(Pr + k0 + 12), ld4(xr + k0 + 12));
    }
    swv[i] = w;

    float qx = lxs[s * NX + i];
#pragma unroll
    for (int k0 = 0; k0 < NX; k0 += 16) {
      qx += dot4(ld4(sAT + i * 68 + k0),      ld4(swv + k0));
      qx += dot4(ld4(sAT + i * 68 + k0 + 4),  ld4(swv + k0 + 4));
      qx += dot4(ld4(sAT + i * 68 + k0 + 8),  ld4(swv + k0 + 8));
      qx += dot4(ld4(sAT + i * 68 + k0 + 12), ld4(swv + k0 + 12));
    }

    float qa = 0.0f;
    const int kb = hh * 32;
#pragma unroll 8
    for (int kk = 0; kk < 32; ++kk)
      qa = fmaf(Bg[(kb + kk) * NU + j], swv[kb + kk], qa);
    qa += __shfl_xor(qa, 32);
    const float qu = qa + lus[s * NU + j];
    if (hh == 0) sqv[j] = qu;

    float ka = dot4(qipre[0], ld4(sqv + hh * 16))
             + dot4(qipre[1], ld4(sqv + hh * 16 + 4))
             + dot4(qipre[2], ld4(sqv + hh * 16 + 8))
             + dot4(qipre[3], ld4(sqv + hh * 16 + 12));
    ka += __shfl_xor(ka, 32);
    if (hh == 0) kv[s * NU + j] = -ka;

    // p = qx + Qxu k   (prefetched gX rows)
    float pp = qx;
#pragma unroll
    for (int m0 = 0; m0 < 8; ++m0)
      pp += dot4(xpre[m0], ld4(kv + s * NU + m0 * 4));
    p_i = pp;
  }

  // flags[0] acquire above covers all gK stores (stage 0 is produced last)
  sdxv[i] = dx_i;
  float4 kcur[8];
  {
    const float* Kr = gK + j * NX + hh * 32;
#pragma unroll
    for (int q = 0; q < 8; ++q) kcur[q] = ld4(Kr + q * 4);
  }
  for (int s = 0; s < NH; ++s) {
    const float* dxh = sdxv + hh * 32;
    float da = 0.0f;
#pragma unroll
    for (int q = 0; q < 8; ++q) da += dot4(kcur[q], ld4(dxh + q * 4));

    // prefetch next stage's K rows (independent of the chain below)
    float4 knxt[8];
    if (s + 1 < NH) {
      const float* Kn = gK + (s + 1) * 2048 + j * NX + hh * 32;
#pragma unroll
      for (int q = 0; q < 8; ++q) knxt[q] = ld4(Kn + q * 4);
    }

    da += __shfl_xor(da, 32);
    const float du = da + kv[s * NU + j];
    if (hh == 0) {
      const int gi = (s * NB + b) * NU + j;
      outp[gi] = ug[gi] + du;
      sduv[j] = du;
    }

    float nxv = xres[s * NX + i];
    const float* Ar = Ag + i * NX;
#pragma unroll
    for (int k0 = 0; k0 < NX; k0 += 4)
      nxv += dot4(ld4(Ar + k0), ld4(sdxv + k0));
    const float* Br = Bg + i * NU;
#pragma unroll
    for (int m0 = 0; m0 < NU; m0 += 4)
      nxv += dot4(ld4(Br + m0), ld4(sduv + m0));
    sdxv[i] = nxv;

    if (s + 1 < NH) {
#pragma unroll
      for (int q = 0; q < 8; ++q) kcur[q] = knxt[q];
    }
  }
}

__global__ void k_zero(float* ws) {
  if (threadIdx.x < 64) ((int*)(ws + WS_P))[threadIdx.x] = 0;
}

__global__ __launch_bounds__(512) void k_fused(
    const float* __restrict__ x0g, const float* __restrict__ xg,
    const float* __restrict__ ug, const float* __restrict__ lg,
    const float* __restrict__ Ag, const float* __restrict__ Bg,
    const float* __restrict__ Qxg, const float* __restrict__ Rug,
    const float* __restrict__ Qfg, float* __restrict__ ws,
    float* __restrict__ outp) {
  __shared__ __align__(16) char smem[SMEMB];
  if (blockIdx.x == 0)
    producer(smem, Ag, Bg, Qxg, Rug, Qfg, ws);
  else
    consumer((float*)smem, blockIdx.x - 1, x0g, xg, ug, lg, Ag, Bg, Qxg, Rug,
             Qfg, ws, outp);
}

extern "C" void kernel_launch(void* const* d_in, const int* in_sizes, int n_in,
                              void* d_out, int out_size, void* d_ws, size_t ws_size,
                              hipStream_t stream) {
  const float* x0  = (const float*)d_in[0];
  const float* x   = (const float*)d_in[1];
  const float* u   = (const float*)d_in[2];
  const float* lmd = (const float*)d_in[3];
  const float* A   = (const float*)d_in[4];
  const float* Bm  = (const float*)d_in[5];
  const float* Qx  = (const float*)d_in[6];
  const float* Ru  = (const float*)d_in[7];
  const float* Qf  = (const float*)d_in[8];
  float* ws  = (float*)d_ws;
  float* out = (float*)d_out;

  hipLaunchKernelGGL(k_zero, dim3(1), dim3(64), 0, stream, ws);
  hipLaunchKernelGGL(k_fused, dim3(NB + 1), dim3(512), 0, stream,
                     x0, x, u, lmd, A, Bm, Qx, Ru, Qf, ws, out);
}

// Round 12
// 446.084 us; speedup vs baseline: 1.0276x; 1.0276x over previous
//
#include <hip/hip_runtime.h>

#define DEV __device__ __forceinline__

constexpr int NX = 64, NU = 32, NH = 32, NB = 192;

// workspace float offsets
constexpr int WS_P   = 0;                            // [NH+1][4096]; slot 0 -> flags
constexpr int WS_QI  = WS_P  + (NH + 1) * NX * NX;   // [NH][1024]  Quu^{-1}
constexpr int WS_X   = WS_QI + NH * NU * NU;         // [NH][64*32] Qxu x-major
constexpr int WS_K   = WS_X  + NH * NX * NU;         // [NH][32*64] K u-major
constexpr int WS_STG = WS_K  + NH * NU * NX;         // [4096] Qxx staging (producer only)

typedef __attribute__((ext_vector_type(8))) short bf16x8;
typedef __attribute__((ext_vector_type(4))) float f32x4;
typedef __attribute__((ext_vector_type(4))) unsigned short us4;

// producer LDS byte offsets. ALL packs 3-level bf16. Big packs row stride
// 72 el (144 B); small packs stride 40 el (80 B). TT 96 rows: G rows 0-63,
// V rows 64-95 (co-computed in Ph1).
constexpr int LVL_M2T = 96 * 72 * 2;   // 13824
constexpr int LVL_P   = 64 * 72 * 2;   //  9216
constexpr int LVL_TT  = 96 * 72 * 2;   // 13824
constexpr int LVL_XU  = 64 * 40 * 2;   //  5120
constexpr int LVL_KT  = 64 * 40 * 2;   //  5120
constexpr int LVL_QI  = 32 * 40 * 2;   //  2560
constexpr int oM2T = 0;
constexpr int oP   = oM2T + 3 * LVL_M2T;   //  41472
constexpr int oTT  = oP   + 3 * LVL_P;     //  69120
constexpr int oXU  = oTT  + 3 * LVL_TT;    // 110592
constexpr int oKT  = oXU  + 3 * LVL_XU;    // 125952
constexpr int oQI  = oKT  + 3 * LVL_KT;    // 141312
constexpr int oQUU = oQI  + 3 * LVL_QI;    // 148992 (fp32 32x36)
constexpr int SMEMB = oQUU + 32 * 36 * 4;  // 153600

DEV unsigned short bfh(float x) {
  unsigned u = __float_as_uint(x);
  return (unsigned short)((u + 0x7FFFu + ((u >> 16) & 1u)) >> 16);
}
DEV float bf2f(unsigned short h) { return __uint_as_float(((unsigned)h) << 16); }
DEV void split3(float x, unsigned short& h, unsigned short& m, unsigned short& l) {
  h = bfh(x); float r1 = x - bf2f(h);
  m = bfh(r1); float r2 = r1 - bf2f(m);
  l = bfh(r2);
}
DEV float4 ld4(const float* p) { return *reinterpret_cast<const float4*>(p); }
DEV void   st4(float* p, float4 v) { *reinterpret_cast<float4*>(p) = v; }
DEV void   st4_nt(float* p, f32x4 v) {
  __builtin_nontemporal_store(v, (f32x4*)p);
}
DEV float  dot4(float4 a, float4 b) {
  return fmaf(a.x, b.x, fmaf(a.y, b.y, fmaf(a.z, b.z, a.w * b.w)));
}
DEV void fma4(float4& a, float s, float4 b) {
  a.x = fmaf(s, b.x, a.x); a.y = fmaf(s, b.y, a.y);
  a.z = fmaf(s, b.z, a.z); a.w = fmaf(s, b.w, a.w);
}
DEV void fma8(float* acc, float s, float4 b0, float4 b1) {
  acc[0] = fmaf(s, b0.x, acc[0]); acc[1] = fmaf(s, b0.y, acc[1]);
  acc[2] = fmaf(s, b0.z, acc[2]); acc[3] = fmaf(s, b0.w, acc[3]);
  acc[4] = fmaf(s, b1.x, acc[4]); acc[5] = fmaf(s, b1.y, acc[5]);
  acc[6] = fmaf(s, b1.z, acc[6]); acc[7] = fmaf(s, b1.w, acc[7]);
}

#define MFMA16(a, b, c) __builtin_amdgcn_mfma_f32_16x16x32_bf16(a, b, c, 0, 0, 0)

// 3-level x 3-level product (error ~2^-26): 6 MFMAs split into TWO independent
// accumulator chains (3 each) — halves the serial MFMA-latency chain per tile.
DEV void prod33p(const char* A, int ao, int LA, const char* B, int bo, int LB,
                 f32x4& accA, f32x4& accB) {
  const bf16x8 a0 = *(const bf16x8*)(A + ao);
  const bf16x8 a1 = *(const bf16x8*)(A + LA + ao);
  const bf16x8 a2 = *(const bf16x8*)(A + 2 * LA + ao);
  const bf16x8 b0 = *(const bf16x8*)(B + bo);
  const bf16x8 b1 = *(const bf16x8*)(B + LB + bo);
  const bf16x8 b2 = *(const bf16x8*)(B + 2 * LB + bo);
  accA = MFMA16(a1, b1, accA);   // chain A: small terms first
  accB = MFMA16(a2, b0, accB);   // chain B
  accA = MFMA16(a0, b2, accA);
  accB = MFMA16(a1, b0, accB);
  accA = MFMA16(a0, b1, accA);
  accB = MFMA16(a0, b0, accB);
}
DEV void st_pack3(char* base, int lvl, int el, f32x4 v) {
  us4 h, m, l;
#pragma unroll
  for (int r = 0; r < 4; ++r) {
    unsigned short hh, mm, ll; split3(v[r], hh, mm, ll);
    h[r] = (short)hh; m[r] = (short)mm; l[r] = (short)ll;
  }
  *(us4*)(base + el * 2) = h;
  *(us4*)(base + lvl + el * 2) = m;
  *(us4*)(base + 2 * lvl + el * 2) = l;
}

// ---------------------------------------------------------------------------
// Producer (block 0, 512 threads): split-bf16 MFMA Riccati recursion.
// Ph1: G+V. Ph2: Quu+Qxu. Ph3: 2-pivot GJ || Qxx->gStage. Ph4: K -> flag.
// Ph5: P'. NT stores for consumer-facing data; release-only flag (R10-valid).
// ---------------------------------------------------------------------------
DEV void producer(char* smem, const float* Ag, const float* Bg,
                  const float* Qxg, const float* Rug, const float* Qfg,
                  float* ws) {
  const int t = threadIdx.x, lane = t & 63, wv = t >> 6;
  const int l15 = lane & 15, l4 = lane >> 4;

  char* M2T = smem + oM2T;
  char* Pp  = smem + oP;
  char* TT  = smem + oTT;     // G rows 0-63, V rows 64-95
  char* XU  = smem + oXU;
  char* KT  = smem + oKT;
  char* QI  = smem + oQI;
  float* QUU = (float*)(smem + oQUU);

  float* gP   = ws + WS_P;
  float* gQI  = ws + WS_QI;
  float* gX   = ws + WS_X;
  float* gK   = ws + WS_K;
  float* gStg = ws + WS_STG;
  int* flags  = (int*)(ws + WS_P);    // [0..31] stage flags

  // ---- static packs: M2T[j][m] = (j<64 ? A[m][j] : B[m][j-64]); P=Qf; gP[32]
  for (int idx = t; idx < 96 * 64; idx += 512) {
    const int j = idx >> 6, m = idx & 63;
    const float v = (j < 64) ? Ag[m * 64 + j] : Bg[m * 32 + (j - 64)];
    unsigned short h, mi, lo; split3(v, h, mi, lo);
    const int eo = (j * 72 + m) * 2;
    *(unsigned short*)(M2T + eo) = h;
    *(unsigned short*)(M2T + LVL_M2T + eo) = mi;
    *(unsigned short*)(M2T + 2 * LVL_M2T + eo) = lo;
  }
  for (int idx = t; idx < 64 * 64; idx += 512) {
    const int r = idx >> 6, c = idx & 63;
    const float v = Qfg[idx];
    unsigned short h, mi, lo; split3(v, h, mi, lo);
    const int eo = (r * 72 + c) * 2;
    *(unsigned short*)(Pp + eo) = h;
    *(unsigned short*)(Pp + LVL_P + eo) = mi;
    *(unsigned short*)(Pp + 2 * LVL_P + eo) = lo;
    __builtin_nontemporal_store(v, gP + 32 * 4096 + idx);
  }
  __syncthreads();

  for (int s = NH - 1; s >= 0; --s) {
    // ---- Ph1: [G|V] = P*[A|B] -> TT. 24 tiles, 3/wave, 6 indep MFMA chains.
#pragma unroll
    for (int q = 0; q < 3; ++q) {
      const int tt = wv + q * 8;
      const int isV = tt >= 16;
      const int t2 = isV ? tt - 16 : tt;
      const int mT = t2 & 3;
      const int br = (isV ? 64 : 0) + (t2 >> 2) * 16;   // B-op / dest row base
      f32x4 aA = {0.f, 0.f, 0.f, 0.f}, aB = {0.f, 0.f, 0.f, 0.f};
#pragma unroll
      for (int kp = 0; kp < 2; ++kp) {
        const int ao = ((mT * 16 + l15) * 72 + kp * 32 + l4 * 8) * 2;
        const int bo = ((br + l15) * 72 + kp * 32 + l4 * 8) * 2;
        prod33p(Pp, ao, LVL_P, M2T, bo, LVL_M2T, aA, aB);
      }
      const f32x4 acc = aA + aB;
      st_pack3(TT, LVL_TT, (br + l15) * 72 + mT * 16 + l4 * 4, acc);
    }
    __syncthreads();

    // ---- Ph2: waves 0-3: Quu = Ru + B^T V ; waves 4-7: Qxu -> XU pack3 + gX
    if (wv < 4) {
      const int uA = wv >> 1, uB = wv & 1;
      f32x4 aA = {0.f, 0.f, 0.f, 0.f}, aB = {0.f, 0.f, 0.f, 0.f};
#pragma unroll
      for (int kp = 0; kp < 2; ++kp) {
        const int ao = ((64 + uA * 16 + l15) * 72 + kp * 32 + l4 * 8) * 2; // V
        const int bo = ((64 + uB * 16 + l15) * 72 + kp * 32 + l4 * 8) * 2; // B
        prod33p(TT, ao, LVL_TT, M2T, bo, LVL_M2T, aA, aB);
      }
      const f32x4 acc = aA + aB;
      const int c = uB * 16 + l15, u0 = uA * 16 + l4 * 4;  // symmetric store
      const float4 rv = ld4(Rug + c * 32 + u0);
      QUU[c * 36 + u0 + 0] = acc[0] + rv.x;
      QUU[c * 36 + u0 + 1] = acc[1] + rv.y;
      QUU[c * 36 + u0 + 2] = acc[2] + rv.z;
      QUU[c * 36 + u0 + 3] = acc[3] + rv.w;
    } else {
#pragma unroll
      for (int q = 0; q < 2; ++q) {
        const int tt = (wv - 4) * 2 + q;     // 0..7
        const int uT = tt & 1, xT = tt >> 1;
        f32x4 aA = {0.f, 0.f, 0.f, 0.f}, aB = {0.f, 0.f, 0.f, 0.f};
#pragma unroll
        for (int kp = 0; kp < 2; ++kp) {
          const int ao = ((64 + uT * 16 + l15) * 72 + kp * 32 + l4 * 8) * 2; // V
          const int bo = ((xT * 16 + l15) * 72 + kp * 32 + l4 * 8) * 2;      // A
          prod33p(TT, ao, LVL_TT, M2T, bo, LVL_M2T, aA, aB);
        }
        const f32x4 acc = aA + aB;
        const int x = xT * 16 + l15, u0 = uT * 16 + l4 * 4;
        st_pack3(XU, LVL_XU, x * 40 + u0, acc);
        st4_nt(gX + s * 2048 + x * 32 + u0, acc);
      }
    }
    __syncthreads();

    // ---- Ph3: wave 0: 2-pivot register GJ inverse ; waves 1-7: Qxx -> gStg
    if (wv == 0) {
      const int i = lane & 31, h = lane >> 5;
      float W[16];
#pragma unroll
      for (int r = 0; r < 16; ++r) W[r] = QUU[i * 36 + h * 16 + r];
#pragma unroll
      for (int q = 0; q < 16; ++q) {
        const int p0 = 2 * q, p1 = 2 * q + 1;
        const int jh = p0 >> 4, jr0 = p0 & 15, jr1 = jr0 + 1;
        const float a = __shfl(W[jr0], p0 | (jh << 5));
        const float b = __shfl(W[jr1], p0 | (jh << 5));
        const float c = __shfl(W[jr0], p1 | (jh << 5));
        const float d = __shfl(W[jr1], p1 | (jh << 5));
        const float rdet = 1.0f / fmaf(a, d, -b * c);
        const float Di00 = d * rdet, Di01 = -b * rdet;
        const float Di10 = -c * rdet, Di11 = a * rdet;
        const float f0 = __shfl(W[jr0], i | (jh << 5));
        const float f1 = __shfl(W[jr1], i | (jh << 5));
        float pr0[16], pr1[16];
#pragma unroll
        for (int r = 0; r < 16; ++r) {
          pr0[r] = __shfl(W[r], p0 | (h << 5));
          pr1[r] = __shfl(W[r], p1 | (h << 5));
        }
        const float g0 = fmaf(f0, Di00, f1 * Di10);
        const float g1 = fmaf(f0, Di01, f1 * Di11);
        float nw[16];
        if (i == p0) {
#pragma unroll
          for (int r = 0; r < 16; ++r) nw[r] = fmaf(Di00, pr0[r], Di01 * pr1[r]);
          if (h == jh) { nw[jr0] = Di00; nw[jr1] = Di01; }
        } else if (i == p1) {
#pragma unroll
          for (int r = 0; r < 16; ++r) nw[r] = fmaf(Di10, pr0[r], Di11 * pr1[r]);
          if (h == jh) { nw[jr0] = Di10; nw[jr1] = Di11; }
        } else {
#pragma unroll
          for (int r = 0; r < 16; ++r)
            nw[r] = fmaf(-g0, pr0[r], fmaf(-g1, pr1[r], W[r]));
          if (h == jh) { nw[jr0] = -g0; nw[jr1] = -g1; }
        }
#pragma unroll
        for (int r = 0; r < 16; ++r) W[r] = nw[r];
      }
#pragma unroll
      for (int q = 0; q < 4; ++q) {
        f32x4 o = {W[4 * q], W[4 * q + 1], W[4 * q + 2], W[4 * q + 3]};
        st4_nt(gQI + s * 1024 + i * 32 + h * 16 + 4 * q, o);
        st_pack3(QI, LVL_QI, i * 40 + h * 16 + 4 * q, o);
      }
    } else {
#pragma unroll
      for (int q = 0; q < 3; ++q) {
        const int tt = (wv - 1) + q * 7;
        if (tt < 16) {
          const int jT = tt >> 2, iT = tt & 3;
          f32x4 aA = {0.f, 0.f, 0.f, 0.f}, aB = {0.f, 0.f, 0.f, 0.f};
#pragma unroll
          for (int kp = 0; kp < 2; ++kp) {
            const int ao = ((jT * 16 + l15) * 72 + kp * 32 + l4 * 8) * 2; // G
            const int bo = ((iT * 16 + l15) * 72 + kp * 32 + l4 * 8) * 2; // A
            prod33p(TT, ao, LVL_TT, M2T, bo, LVL_M2T, aA, aB);
          }
          const f32x4 acc = aA + aB;
          const int c = iT * 16 + l15, j0 = jT * 16 + l4 * 4;
          const float4 qv = ld4(Qxg + c * 64 + j0);
          float4 o; o.x = acc[0] + qv.x; o.y = acc[1] + qv.y;
          o.z = acc[2] + qv.z; o.w = acc[3] + qv.w;
          st4(gStg + c * 64 + j0, o);      // producer-L2 hot
        }
      }
    }
    __syncthreads();

    // ---- Ph4: K = QI*Qxu^T, 8 tiles, 1/wave. gK NT; KT pack3.
    {
      const int mT = wv & 1, xT = wv >> 1;
      f32x4 aA = {0.f, 0.f, 0.f, 0.f}, aB = {0.f, 0.f, 0.f, 0.f};
      const int ao = ((mT * 16 + l15) * 40 + l4 * 8) * 2;
      const int bo = ((xT * 16 + l15) * 40 + l4 * 8) * 2;
      prod33p(QI, ao, LVL_QI, XU, bo, LVL_XU, aA, aB);
      const f32x4 acc = aA + aB;
      const int x = xT * 16 + l15, m0 = mT * 16 + l4 * 4;
#pragma unroll
      for (int r = 0; r < 4; ++r)
        __builtin_nontemporal_store(-acc[r], gK + s * 2048 + (m0 + r) * 64 + x);
      st_pack3(KT, LVL_KT, x * 40 + m0, acc);
    }
    __syncthreads();

    // publish stage s (gP[s+1] prev Ph5; gX Ph2; gQI Ph3; gK Ph4 — drained by
    // barriers; release-scope store orders them)
    if (t == 0)
      __hip_atomic_store(flags + s, 1, __ATOMIC_RELEASE, __HIP_MEMORY_SCOPE_AGENT);

    // ---- Ph5: P' = Qxx - Qxu*K ; gP[s] NT + P pack3. Skip s=0.
    if (s > 0) {
#pragma unroll
      for (int q = 0; q < 2; ++q) {
        const int tt = wv + q * 8;
        const int iT = tt & 3, jT = tt >> 2;
        f32x4 aA = {0.f, 0.f, 0.f, 0.f}, aB = {0.f, 0.f, 0.f, 0.f};
        const int ao = ((iT * 16 + l15) * 40 + l4 * 8) * 2;
        const int bo = ((jT * 16 + l15) * 40 + l4 * 8) * 2;
        prod33p(XU, ao, LVL_XU, KT, bo, LVL_KT, aA, aB);
        const f32x4 acc = aA + aB;
        const int j = jT * 16 + l15, i0 = iT * 16 + l4 * 4;
        const float4 qx4 = ld4(gStg + j * 64 + i0);   // Qxx(j,i0..)=Qxx(i0..,j)
        f32x4 pv;
        pv[0] = qx4.x - acc[0]; pv[1] = qx4.y - acc[1];
        pv[2] = qx4.z - acc[2]; pv[3] = qx4.w - acc[3];
#pragma unroll
        for (int r = 0; r < 4; ++r)
          __builtin_nontemporal_store(pv[r], gP + s * 4096 + (i0 + r) * 64 + j);
        st_pack3(Pp, LVL_P, j * 72 + i0, pv);  // symmetry: pack[j][i]=P'[i][j]
      }
    }
    __syncthreads();
  }
}

// ---------------------------------------------------------------------------
// Consumer: per-batch residuals (threads 0-255) + wave-0 recursions.
// Backward gated per-stage on flags[s]; flags[0] (last) covers all gK.
// (R10 consumer, verbatim.)
// ---------------------------------------------------------------------------
DEV void consumer(float* lds, int b, const float* x0g, const float* xg,
                  const float* ug, const float* lg, const float* Ag,
                  const float* Bg, const float* Qxg, const float* Rug,
                  const float* Qfg, float* ws, float* outp) {
  const int t = threadIdx.x;
  const float* gP  = ws + WS_P;
  const float* gQI = ws + WS_QI;
  const float* gX  = ws + WS_X;
  const float* gK  = ws + WS_K;
  int* flags = (int*)(ws + WS_P);

  float* sx   = lds;            // 2112 (dead after residuals)
  float* sl   = lds + 2112;     // 2112 (dead after residuals)
  float* su   = lds + 4224;     // 1024 (dead after residuals)
  float* sAT  = lds;            // overlay, stride 68
  float* xres = lds + 5248;     // 2048
  float* lxs  = lds + 7296;     // 2048
  float* lus  = lds + 9344;     // 1024
  float* kv   = lds + 10368;    // 1024
  float* swv  = lds + 11392;    // 64
  float* sqv  = lds + 11456;    // 32
  float* sduv = lds + 11488;    // 32
  float* sdxv = lds + 11520;    // 64

  for (int idx = t; idx < (NH + 1) * NX; idx += 512) {
    const int s = idx >> 6, i = idx & 63;
    sx[idx] = xg[(s * NB + b) * NX + i];
    sl[idx] = lg[(s * NB + b) * NX + i];
  }
  for (int idx = t; idx < NH * NU; idx += 512) {
    const int s = idx >> 5, j = idx & 31;
    su[idx] = ug[(s * NB + b) * NU + j];
  }
  __syncthreads();

  if (t < 256) {
    const int s = t >> 3, i0 = (t & 7) * 8;
    float accx[8], accl[8];
#pragma unroll
    for (int ii = 0; ii < 8; ++ii) {
      accx[ii] = -sx[(s + 1) * NX + i0 + ii];
      accl[ii] = -sl[s * NX + i0 + ii];
    }
#pragma unroll 2
    for (int k0 = 0; k0 < NX; k0 += 4) {
      const float4 xv = ld4(sx + s * NX + k0);
#pragma unroll
      for (int ii = 0; ii < 8; ++ii) {
        accx[ii] += dot4(ld4(Ag + (i0 + ii) * NX + k0), xv);
        accl[ii] += dot4(ld4(Qxg + (i0 + ii) * NX + k0), xv);
      }
    }
#pragma unroll 2
    for (int k0 = 0; k0 < NU; k0 += 4) {
      const float4 uv = ld4(su + s * NU + k0);
#pragma unroll
      for (int ii = 0; ii < 8; ++ii)
        accx[ii] += dot4(ld4(Bg + (i0 + ii) * NU + k0), uv);
    }
#pragma unroll 4
    for (int k = 0; k < NX; ++k) {
      const float lv = sl[(s + 1) * NX + k];
      fma8(accl, lv, ld4(Ag + k * NX + i0), ld4(Ag + k * NX + i0 + 4));
    }
#pragma unroll
    for (int ii = 0; ii < 8; ++ii) {
      xres[s * NX + i0 + ii] = accx[ii];
      lxs[s * NX + i0 + ii] = accl[ii];
    }
  }
  if (t < 256) {
    const int s = t >> 3, j0 = (t & 7) * 4;
    float4 acc = {0, 0, 0, 0};
#pragma unroll 2
    for (int k0 = 0; k0 < NU; k0 += 4) {
      const float4 uv = ld4(su + s * NU + k0);
      acc.x += dot4(ld4(Rug + (j0 + 0) * NU + k0), uv);
      acc.y += dot4(ld4(Rug + (j0 + 1) * NU + k0), uv);
      acc.z += dot4(ld4(Rug + (j0 + 2) * NU + k0), uv);
      acc.w += dot4(ld4(Rug + (j0 + 3) * NU + k0), uv);
    }
#pragma unroll 4
    for (int k = 0; k < NX; ++k) {
      const float lv = sl[(s + 1) * NX + k];
      fma4(acc, lv, ld4(Bg + k * NU + j0));
    }
    lus[s * NU + j0 + 0] = acc.x; lus[s * NU + j0 + 1] = acc.y;
    lus[s * NU + j0 + 2] = acc.z; lus[s * NU + j0 + 3] = acc.w;
  }

  float p_i = 0.0f, dx_i = 0.0f;
  if (t < 64) {
    const int i = t;
    float acc = -sl[NH * NX + i];
#pragma unroll 4
    for (int k0 = 0; k0 < NX; k0 += 4)
      acc += dot4(ld4(Qfg + i * NX + k0), ld4(sx + NH * NX + k0));
    p_i = acc;
    dx_i = x0g[b * NX + i] - sx[i];
  }
  __syncthreads();

  for (int idx = t; idx < NX * NX / 4; idx += 512) {
    const int k = idx >> 4, i4 = (idx & 15) * 4;
    const float4 a4 = ld4(Ag + k * NX + i4);
    sAT[(i4 + 0) * 68 + k] = a4.x;
    sAT[(i4 + 1) * 68 + k] = a4.y;
    sAT[(i4 + 2) * 68 + k] = a4.z;
    sAT[(i4 + 3) * 68 + k] = a4.w;
  }
  __syncthreads();

  if (t >= 64) return;   // wave 0 continues barrier-free

  const int i = t;
  const int j = t & 31;
  const int hh = t >> 5;

  for (int s = NH - 1; s >= 0; --s) {
    // relaxed poll; single acquire on success
    while (__hip_atomic_load(flags + s, __ATOMIC_RELAXED,
                             __HIP_MEMORY_SCOPE_AGENT) == 0)
      __builtin_amdgcn_s_sleep(4);
    (void)__hip_atomic_load(flags + s, __ATOMIC_ACQUIRE,
                            __HIP_MEMORY_SCOPE_AGENT);

    const float* Pr = gP + (s + 1) * NX * NX + i * NX;
    const float* xr = xres + s * NX;
    float w = p_i;
#pragma unroll
    for (int k0 = 0; k0 < NX; k0 += 16) {
      w += dot4(ld4(Pr + k0),      ld4(xr + k0));
      w += dot4(ld4(Pr + k0 + 4),  ld4(xr + k0 + 4));
      w += dot4(ld4(Pr + k0 + 8),  ld4(xr + k0 + 8));
      w += dot4(ld4(Pr + k0 + 12), ld4(xr + k0 + 12));
    }
    swv[i] = w;

    float qx = lxs[s * NX + i];
#pragma unroll
    for (int k0 = 0; k0 < NX; k0 += 16) {
      qx += dot4(ld4(sAT + i * 68 + k0),      ld4(swv + k0));
      qx += dot4(ld4(sAT + i * 68 + k0 + 4),  ld4(swv + k0 + 4));
      qx += dot4(ld4(sAT + i * 68 + k0 + 8),  ld4(swv + k0 + 8));
      qx += dot4(ld4(sAT + i * 68 + k0 + 12), ld4(swv + k0 + 12));
    }

    float qa = 0.0f;
    const int kb = hh * 32;
#pragma unroll 8
    for (int kk = 0; kk < 32; ++kk)
      qa = fmaf(Bg[(kb + kk) * NU + j], swv[kb + kk], qa);
    qa += __shfl_xor(qa, 32);
    const float qu = qa + lus[s * NU + j];
    if (hh == 0) sqv[j] = qu;

    const float* Qr = gQI + s * NU * NU + j * NU + hh * 16;
    float ka = dot4(ld4(Qr),      ld4(sqv + hh * 16))
             + dot4(ld4(Qr + 4),  ld4(sqv + hh * 16 + 4))
             + dot4(ld4(Qr + 8),  ld4(sqv + hh * 16 + 8))
             + dot4(ld4(Qr + 12), ld4(sqv + hh * 16 + 12));
    ka += __shfl_xor(ka, 32);
    if (hh == 0) kv[s * NU + j] = -ka;

    // p = qx + Qxu k   (gX x-major: lane i reads 32 contiguous floats)
    const float* Xs = gX + s * 2048 + i * 32;
    float pp = qx;
#pragma unroll
    for (int m0 = 0; m0 < NU; m0 += 4)
      pp += dot4(ld4(Xs + m0), ld4(kv + s * NU + m0));
    p_i = pp;
  }

  // flags[0] acquire above covers all gK stores (stage 0 is produced last)
  sdxv[i] = dx_i;
  for (int s = 0; s < NH; ++s) {
    const float* Kr = gK + s * NU * NX + j * NX + hh * 32;
    const float* dxh = sdxv + hh * 32;
    float da = 0.0f;
#pragma unroll
    for (int k0 = 0; k0 < 32; k0 += 16) {
      da += dot4(ld4(Kr + k0),      ld4(dxh + k0));
      da += dot4(ld4(Kr + k0 + 4),  ld4(dxh + k0 + 4));
      da += dot4(ld4(Kr + k0 + 8),  ld4(dxh + k0 + 8));
      da += dot4(ld4(Kr + k0 + 12), ld4(dxh + k0 + 12));
    }
    da += __shfl_xor(da, 32);
    const float du = da + kv[s * NU + j];
    if (hh == 0) {
      const int gi = (s * NB + b) * NU + j;
      outp[gi] = ug[gi] + du;
      sduv[j] = du;
    }

    float nxv = xres[s * NX + i];
    const float* Ar = Ag + i * NX;
#pragma unroll
    for (int k0 = 0; k0 < NX; k0 += 4)
      nxv += dot4(ld4(Ar + k0), ld4(sdxv + k0));
    const float* Br = Bg + i * NU;
#pragma unroll
    for (int m0 = 0; m0 < NU; m0 += 4)
      nxv += dot4(ld4(Br + m0), ld4(sduv + m0));
    sdxv[i] = nxv;
  }
}

__global__ void k_zero(float* ws) {
  if (threadIdx.x < 64) ((int*)(ws + WS_P))[threadIdx.x] = 0;
}

__global__ __launch_bounds__(512) void k_fused(
    const float* __restrict__ x0g, const float* __restrict__ xg,
    const float* __restrict__ ug, const float* __restrict__ lg,
    const float* __restrict__ Ag, const float* __restrict__ Bg,
    const float* __restrict__ Qxg, const float* __restrict__ Rug,
    const float* __restrict__ Qfg, float* __restrict__ ws,
    float* __restrict__ outp) {
  __shared__ __align__(16) char smem[SMEMB];
  if (blockIdx.x == 0)
    producer(smem, Ag, Bg, Qxg, Rug, Qfg, ws);
  else
    consumer((float*)smem, blockIdx.x - 1, x0g, xg, ug, lg, Ag, Bg, Qxg, Rug,
             Qfg, ws, outp);
}

extern "C" void kernel_launch(void* const* d_in, const int* in_sizes, int n_in,
                              void* d_out, int out_size, void* d_ws, size_t ws_size,
                              hipStream_t stream) {
  const float* x0  = (const float*)d_in[0];
  const float* x   = (const float*)d_in[1];
  const float* u   = (const float*)d_in[2];
  const float* lmd = (const float*)d_in[3];
  const float* A   = (const float*)d_in[4];
  const float* Bm  = (const float*)d_in[5];
  const float* Qx  = (const float*)d_in[6];
  const float* Ru  = (const float*)d_in[7];
  const float* Qf  = (const float*)d_in[8];
  float* ws  = (float*)d_ws;
  float* out = (float*)d_out;

  hipLaunchKernelGGL(k_zero, dim3(1), dim3(64), 0, stream, ws);
  hipLaunchKernelGGL(k_fused, dim3(NB + 1), dim3(512), 0, stream,
                     x0, x, u, lmd, A, Bm, Qx, Ru, Qf, ws, out);
}

// Round 13
// 401.327 us; speedup vs baseline: 1.1422x; 1.1115x over previous
//
#include <hip/hip_runtime.h>

#define DEV __device__ __forceinline__

constexpr int NX = 64, NU = 32, NH = 32, NB = 192;

// workspace float offsets
constexpr int WS_P   = 0;                            // [NH+1][4096]; slot 0 -> flags
constexpr int WS_QI  = WS_P  + (NH + 1) * NX * NX;   // [NH][1024]  Quu^{-1}
constexpr int WS_X   = WS_QI + NH * NU * NU;         // [NH][64*32] Qxu x-major
constexpr int WS_K   = WS_X  + NH * NX * NU;         // [NH][32*64] K u-major
constexpr int WS_STG = WS_K  + NH * NU * NX;         // [4096] Qxx staging (producer only)

typedef __attribute__((ext_vector_type(8))) short bf16x8;
typedef __attribute__((ext_vector_type(4))) float f32x4;
typedef __attribute__((ext_vector_type(4))) unsigned short us4;

// producer LDS byte offsets. ALL packs 3-level bf16. Big packs row stride
// 72 el (144 B); small packs stride 40 el (80 B). TT 96 rows: G rows 0-63,
// V rows 64-95 (co-computed in Ph1).
constexpr int LVL_M2T = 96 * 72 * 2;   // 13824
constexpr int LVL_P   = 64 * 72 * 2;   //  9216
constexpr int LVL_TT  = 96 * 72 * 2;   // 13824
constexpr int LVL_XU  = 64 * 40 * 2;   //  5120
constexpr int LVL_KT  = 64 * 40 * 2;   //  5120
constexpr int LVL_QI  = 32 * 40 * 2;   //  2560
constexpr int oM2T = 0;
constexpr int oP   = oM2T + 3 * LVL_M2T;   //  41472
constexpr int oTT  = oP   + 3 * LVL_P;     //  69120
constexpr int oXU  = oTT  + 3 * LVL_TT;    // 110592
constexpr int oKT  = oXU  + 3 * LVL_XU;    // 125952
constexpr int oQI  = oKT  + 3 * LVL_KT;    // 141312
constexpr int oQUU = oQI  + 3 * LVL_QI;    // 148992 (fp32 32x36)
constexpr int SMEMB = oQUU + 32 * 36 * 4;  // 153600

DEV unsigned short bfh(float x) {
  unsigned u = __float_as_uint(x);
  return (unsigned short)((u + 0x7FFFu + ((u >> 16) & 1u)) >> 16);
}
DEV float bf2f(unsigned short h) { return __uint_as_float(((unsigned)h) << 16); }
DEV void split3(float x, unsigned short& h, unsigned short& m, unsigned short& l) {
  h = bfh(x); float r1 = x - bf2f(h);
  m = bfh(r1); float r2 = r1 - bf2f(m);
  l = bfh(r2);
}
DEV float4 ld4(const float* p) { return *reinterpret_cast<const float4*>(p); }
DEV void   st4(float* p, float4 v) { *reinterpret_cast<float4*>(p) = v; }
DEV void   st4_nt(float* p, f32x4 v) {
  __builtin_nontemporal_store(v, (f32x4*)p);
}
DEV float  dot4(float4 a, float4 b) {
  return fmaf(a.x, b.x, fmaf(a.y, b.y, fmaf(a.z, b.z, a.w * b.w)));
}
DEV void fma4(float4& a, float s, float4 b) {
  a.x = fmaf(s, b.x, a.x); a.y = fmaf(s, b.y, a.y);
  a.z = fmaf(s, b.z, a.z); a.w = fmaf(s, b.w, a.w);
}
DEV void fma8(float* acc, float s, float4 b0, float4 b1) {
  acc[0] = fmaf(s, b0.x, acc[0]); acc[1] = fmaf(s, b0.y, acc[1]);
  acc[2] = fmaf(s, b0.z, acc[2]); acc[3] = fmaf(s, b0.w, acc[3]);
  acc[4] = fmaf(s, b1.x, acc[4]); acc[5] = fmaf(s, b1.y, acc[5]);
  acc[6] = fmaf(s, b1.z, acc[6]); acc[7] = fmaf(s, b1.w, acc[7]);
}

#define MFMA16(a, b, c) __builtin_amdgcn_mfma_f32_16x16x32_bf16(a, b, c, 0, 0, 0)

// 3-level x 3-level product (error ~2^-26): 6 MFMAs, small terms first.
DEV f32x4 prod33(const char* A, int ao, int LA, const char* B, int bo, int LB,
                 f32x4 acc) {
  const bf16x8 a0 = *(const bf16x8*)(A + ao);
  const bf16x8 a1 = *(const bf16x8*)(A + LA + ao);
  const bf16x8 a2 = *(const bf16x8*)(A + 2 * LA + ao);
  const bf16x8 b0 = *(const bf16x8*)(B + bo);
  const bf16x8 b1 = *(const bf16x8*)(B + LB + bo);
  const bf16x8 b2 = *(const bf16x8*)(B + 2 * LB + bo);
  acc = MFMA16(a1, b1, acc);
  acc = MFMA16(a2, b0, acc);
  acc = MFMA16(a0, b2, acc);
  acc = MFMA16(a1, b0, acc);
  acc = MFMA16(a0, b1, acc);
  acc = MFMA16(a0, b0, acc);
  return acc;
}
DEV void st_pack3(char* base, int lvl, int el, f32x4 v) {
  us4 h, m, l;
#pragma unroll
  for (int r = 0; r < 4; ++r) {
    unsigned short hh, mm, ll; split3(v[r], hh, mm, ll);
    h[r] = (short)hh; m[r] = (short)mm; l[r] = (short)ll;
  }
  *(us4*)(base + el * 2) = h;
  *(us4*)(base + lvl + el * 2) = m;
  *(us4*)(base + 2 * lvl + el * 2) = l;
}

// ---------------------------------------------------------------------------
// Producer (block 0, 1024 threads / 16 waves, 4 waves/SIMD): split-bf16 MFMA
// Riccati recursion. Ph1: G+V (<=2 tiles/wave). Ph2: Quu+Qxu (1/wave).
// Ph3: GJ || Qxx->gStage (1-2/wave). Ph4: K (1/wave) -> flag. Ph5: P' (1/wave).
// ---------------------------------------------------------------------------
DEV void producer(char* smem, const float* Ag, const float* Bg,
                  const float* Qxg, const float* Rug, const float* Qfg,
                  float* ws) {
  const int t = threadIdx.x, lane = t & 63, wv = t >> 6;   // wv 0..15
  const int l15 = lane & 15, l4 = lane >> 4;

  char* M2T = smem + oM2T;
  char* Pp  = smem + oP;
  char* TT  = smem + oTT;     // G rows 0-63, V rows 64-95
  char* XU  = smem + oXU;
  char* KT  = smem + oKT;
  char* QI  = smem + oQI;
  float* QUU = (float*)(smem + oQUU);

  float* gP   = ws + WS_P;
  float* gQI  = ws + WS_QI;
  float* gX   = ws + WS_X;
  float* gK   = ws + WS_K;
  float* gStg = ws + WS_STG;
  int* flags  = (int*)(ws + WS_P);    // [0..31] stage flags

  // ---- static packs: M2T[j][m] = (j<64 ? A[m][j] : B[m][j-64]); P=Qf; gP[32]
  for (int idx = t; idx < 96 * 64; idx += 1024) {
    const int j = idx >> 6, m = idx & 63;
    const float v = (j < 64) ? Ag[m * 64 + j] : Bg[m * 32 + (j - 64)];
    unsigned short h, mi, lo; split3(v, h, mi, lo);
    const int eo = (j * 72 + m) * 2;
    *(unsigned short*)(M2T + eo) = h;
    *(unsigned short*)(M2T + LVL_M2T + eo) = mi;
    *(unsigned short*)(M2T + 2 * LVL_M2T + eo) = lo;
  }
  for (int idx = t; idx < 64 * 64; idx += 1024) {
    const int r = idx >> 6, c = idx & 63;
    const float v = Qfg[idx];
    unsigned short h, mi, lo; split3(v, h, mi, lo);
    const int eo = (r * 72 + c) * 2;
    *(unsigned short*)(Pp + eo) = h;
    *(unsigned short*)(Pp + LVL_P + eo) = mi;
    *(unsigned short*)(Pp + 2 * LVL_P + eo) = lo;
    __builtin_nontemporal_store(v, gP + 32 * 4096 + idx);
  }
  __syncthreads();

  for (int s = NH - 1; s >= 0; --s) {
    // ---- Ph1: [G|V] = P*[A|B] -> TT. 24 tiles over 16 waves (<=2 each).
    for (int tt = wv; tt < 24; tt += 16) {
      const int isV = tt >= 16;
      const int t2 = isV ? tt - 16 : tt;
      const int mT = t2 & 3;
      const int br = (isV ? 64 : 0) + (t2 >> 2) * 16;   // B-op / dest row base
      f32x4 acc = {0.f, 0.f, 0.f, 0.f};
#pragma unroll
      for (int kp = 0; kp < 2; ++kp) {
        const int ao = ((mT * 16 + l15) * 72 + kp * 32 + l4 * 8) * 2;
        const int bo = ((br + l15) * 72 + kp * 32 + l4 * 8) * 2;
        acc = prod33(Pp, ao, LVL_P, M2T, bo, LVL_M2T, acc);
      }
      st_pack3(TT, LVL_TT, (br + l15) * 72 + mT * 16 + l4 * 4, acc);
    }
    __syncthreads();

    // ---- Ph2: 12 tiles, 1/wave. tt<4: Quu = Ru + B^T V ; tt 4..11: Qxu.
    if (wv < 4) {
      const int uA = wv >> 1, uB = wv & 1;
      f32x4 acc = {0.f, 0.f, 0.f, 0.f};
#pragma unroll
      for (int kp = 0; kp < 2; ++kp) {
        const int ao = ((64 + uA * 16 + l15) * 72 + kp * 32 + l4 * 8) * 2; // V
        const int bo = ((64 + uB * 16 + l15) * 72 + kp * 32 + l4 * 8) * 2; // B
        acc = prod33(TT, ao, LVL_TT, M2T, bo, LVL_M2T, acc);
      }
      const int c = uB * 16 + l15, u0 = uA * 16 + l4 * 4;  // symmetric store
      const float4 rv = ld4(Rug + c * 32 + u0);
      QUU[c * 36 + u0 + 0] = acc[0] + rv.x;
      QUU[c * 36 + u0 + 1] = acc[1] + rv.y;
      QUU[c * 36 + u0 + 2] = acc[2] + rv.z;
      QUU[c * 36 + u0 + 3] = acc[3] + rv.w;
    } else if (wv < 12) {
      const int q = wv - 4;                // 0..7
      const int uT = q & 1, xT = q >> 1;
      f32x4 acc = {0.f, 0.f, 0.f, 0.f};
#pragma unroll
      for (int kp = 0; kp < 2; ++kp) {
        const int ao = ((64 + uT * 16 + l15) * 72 + kp * 32 + l4 * 8) * 2; // V
        const int bo = ((xT * 16 + l15) * 72 + kp * 32 + l4 * 8) * 2;      // A
        acc = prod33(TT, ao, LVL_TT, M2T, bo, LVL_M2T, acc);
      }
      const int x = xT * 16 + l15, u0 = uT * 16 + l4 * 4;
      st_pack3(XU, LVL_XU, x * 40 + u0, acc);
      st4_nt(gX + s * 2048 + x * 32 + u0, acc);
    }
    __syncthreads();

    // ---- Ph3: wave 0: 1-pivot register GJ inverse ; waves 1-15: Qxx -> gStg
    if (wv == 0) {
      const int i = lane & 31, h = lane >> 5;
      float W[16];
#pragma unroll
      for (int r = 0; r < 16; ++r) W[r] = QUU[i * 36 + h * 16 + r];
#pragma unroll
      for (int j = 0; j < 32; ++j) {
        const int jh = j >> 4, jr = j & 15;
        const float d = __shfl(W[jr], j | (jh << 5));
        const float pinv = 1.0f / d;
        const float f = __shfl(W[jr], i | (jh << 5));
        float pr[16];
#pragma unroll
        for (int r = 0; r < 16; ++r) pr[r] = __shfl(W[r], j | (h << 5));
        float nw[16];
        if (i == j) {
#pragma unroll
          for (int r = 0; r < 16; ++r) nw[r] = pr[r] * pinv;
          if (h == jh) nw[jr] = pinv;
        } else {
          const float g = f * pinv;
#pragma unroll
          for (int r = 0; r < 16; ++r) nw[r] = fmaf(-g, pr[r], W[r]);
          if (h == jh) nw[jr] = -g;
        }
#pragma unroll
        for (int r = 0; r < 16; ++r) W[r] = nw[r];
      }
#pragma unroll
      for (int q = 0; q < 4; ++q) {
        f32x4 o = {W[4 * q], W[4 * q + 1], W[4 * q + 2], W[4 * q + 3]};
        st4_nt(gQI + s * 1024 + i * 32 + h * 16 + 4 * q, o);
        st_pack3(QI, LVL_QI, i * 40 + h * 16 + 4 * q, o);
      }
    } else {
      for (int tt = wv - 1; tt < 16; tt += 15) {
        const int jT = tt >> 2, iT = tt & 3;
        f32x4 acc = {0.f, 0.f, 0.f, 0.f};
#pragma unroll
        for (int kp = 0; kp < 2; ++kp) {
          const int ao = ((jT * 16 + l15) * 72 + kp * 32 + l4 * 8) * 2; // G
          const int bo = ((iT * 16 + l15) * 72 + kp * 32 + l4 * 8) * 2; // A
          acc = prod33(TT, ao, LVL_TT, M2T, bo, LVL_M2T, acc);
        }
        const int c = iT * 16 + l15, j0 = jT * 16 + l4 * 4;
        const float4 qv = ld4(Qxg + c * 64 + j0);
        float4 o; o.x = acc[0] + qv.x; o.y = acc[1] + qv.y;
        o.z = acc[2] + qv.z; o.w = acc[3] + qv.w;
        st4(gStg + c * 64 + j0, o);      // normal store, producer-L2 hot
      }
    }
    __syncthreads();

    // ---- Ph4: K = QI*Qxu^T, 8 tiles, waves 0-7. gK NT; KT pack3.
    if (wv < 8) {
      const int mT = wv & 1, xT = wv >> 1;
      f32x4 acc = {0.f, 0.f, 0.f, 0.f};
      const int ao = ((mT * 16 + l15) * 40 + l4 * 8) * 2;
      const int bo = ((xT * 16 + l15) * 40 + l4 * 8) * 2;
      acc = prod33(QI, ao, LVL_QI, XU, bo, LVL_XU, acc);
      const int x = xT * 16 + l15, m0 = mT * 16 + l4 * 4;
#pragma unroll
      for (int r = 0; r < 4; ++r)
        __builtin_nontemporal_store(-acc[r], gK + s * 2048 + (m0 + r) * 64 + x);
      st_pack3(KT, LVL_KT, x * 40 + m0, acc);
    }
    __syncthreads();

    // publish stage s (gP[s+1] prev Ph5; gX Ph2; gQI Ph3; gK Ph4 — all
    // drained by barriers; release-scope store orders them)
    if (t == 0)
      __hip_atomic_store(flags + s, 1, __ATOMIC_RELEASE, __HIP_MEMORY_SCOPE_AGENT);

    // ---- Ph5: P' = Qxx - Qxu*K ; gP[s] NT + P pack3. 16 tiles, 1/wave.
    if (s > 0) {
      const int tt = wv;
      const int iT = tt & 3, jT = tt >> 2;
      f32x4 acc = {0.f, 0.f, 0.f, 0.f};
      const int ao = ((iT * 16 + l15) * 40 + l4 * 8) * 2;
      const int bo = ((jT * 16 + l15) * 40 + l4 * 8) * 2;
      acc = prod33(XU, ao, LVL_XU, KT, bo, LVL_KT, acc);
      const int j = jT * 16 + l15, i0 = iT * 16 + l4 * 4;
      const float4 qx4 = ld4(gStg + j * 64 + i0);   // Qxx(j,i0..)=Qxx(i0..,j)
      f32x4 pv;
      pv[0] = qx4.x - acc[0]; pv[1] = qx4.y - acc[1];
      pv[2] = qx4.z - acc[2]; pv[3] = qx4.w - acc[3];
#pragma unroll
      for (int r = 0; r < 4; ++r)
        __builtin_nontemporal_store(pv[r], gP + s * 4096 + (i0 + r) * 64 + j);
      st_pack3(Pp, LVL_P, j * 72 + i0, pv);  // symmetry: pack[j][i]=P'[i][j]
    }
    __syncthreads();
  }
}

// ---------------------------------------------------------------------------
// Consumer: per-batch residuals (threads 0-255) + wave-0 recursions.
// Backward gated per-stage on flags[s]; flags[0] (last) covers all gK.
// All 1024 threads reach all barriers; waves >0 exit after staging.
// ---------------------------------------------------------------------------
DEV void consumer(float* lds, int b, const float* x0g, const float* xg,
                  const float* ug, const float* lg, const float* Ag,
                  const float* Bg, const float* Qxg, const float* Rug,
                  const float* Qfg, float* ws, float* outp) {
  const int t = threadIdx.x;
  const float* gP  = ws + WS_P;
  const float* gQI = ws + WS_QI;
  const float* gX  = ws + WS_X;
  const float* gK  = ws + WS_K;
  int* flags = (int*)(ws + WS_P);

  float* sx   = lds;            // 2112 (dead after residuals)
  float* sl   = lds + 2112;     // 2112 (dead after residuals)
  float* su   = lds + 4224;     // 1024 (dead after residuals)
  float* sAT  = lds;            // overlay, stride 68
  float* xres = lds + 5248;     // 2048
  float* lxs  = lds + 7296;     // 2048
  float* lus  = lds + 9344;     // 1024
  float* kv   = lds + 10368;    // 1024
  float* swv  = lds + 11392;    // 64
  float* sqv  = lds + 11456;    // 32
  float* sduv = lds + 11488;    // 32
  float* sdxv = lds + 11520;    // 64

  for (int idx = t; idx < (NH + 1) * NX; idx += 1024) {
    const int s = idx >> 6, i = idx & 63;
    sx[idx] = xg[(s * NB + b) * NX + i];
    sl[idx] = lg[(s * NB + b) * NX + i];
  }
  for (int idx = t; idx < NH * NU; idx += 1024) {
    const int s = idx >> 5, j = idx & 31;
    su[idx] = ug[(s * NB + b) * NU + j];
  }
  __syncthreads();

  if (t < 256) {
    const int s = t >> 3, i0 = (t & 7) * 8;
    float accx[8], accl[8];
#pragma unroll
    for (int ii = 0; ii < 8; ++ii) {
      accx[ii] = -sx[(s + 1) * NX + i0 + ii];
      accl[ii] = -sl[s * NX + i0 + ii];
    }
#pragma unroll 2
    for (int k0 = 0; k0 < NX; k0 += 4) {
      const float4 xv = ld4(sx + s * NX + k0);
#pragma unroll
      for (int ii = 0; ii < 8; ++ii) {
        accx[ii] += dot4(ld4(Ag + (i0 + ii) * NX + k0), xv);
        accl[ii] += dot4(ld4(Qxg + (i0 + ii) * NX + k0), xv);
      }
    }
#pragma unroll 2
    for (int k0 = 0; k0 < NU; k0 += 4) {
      const float4 uv = ld4(su + s * NU + k0);
#pragma unroll
      for (int ii = 0; ii < 8; ++ii)
        accx[ii] += dot4(ld4(Bg + (i0 + ii) * NU + k0), uv);
    }
#pragma unroll 4
    for (int k = 0; k < NX; ++k) {
      const float lv = sl[(s + 1) * NX + k];
      fma8(accl, lv, ld4(Ag + k * NX + i0), ld4(Ag + k * NX + i0 + 4));
    }
#pragma unroll
    for (int ii = 0; ii < 8; ++ii) {
      xres[s * NX + i0 + ii] = accx[ii];
      lxs[s * NX + i0 + ii] = accl[ii];
    }
  }
  if (t < 256) {
    const int s = t >> 3, j0 = (t & 7) * 4;
    float4 acc = {0, 0, 0, 0};
#pragma unroll 2
    for (int k0 = 0; k0 < NU; k0 += 4) {
      const float4 uv = ld4(su + s * NU + k0);
      acc.x += dot4(ld4(Rug + (j0 + 0) * NU + k0), uv);
      acc.y += dot4(ld4(Rug + (j0 + 1) * NU + k0), uv);
      acc.z += dot4(ld4(Rug + (j0 + 2) * NU + k0), uv);
      acc.w += dot4(ld4(Rug + (j0 + 3) * NU + k0), uv);
    }
#pragma unroll 4
    for (int k = 0; k < NX; ++k) {
      const float lv = sl[(s + 1) * NX + k];
      fma4(acc, lv, ld4(Bg + k * NU + j0));
    }
    lus[s * NU + j0 + 0] = acc.x; lus[s * NU + j0 + 1] = acc.y;
    lus[s * NU + j0 + 2] = acc.z; lus[s * NU + j0 + 3] = acc.w;
  }

  float p_i = 0.0f, dx_i = 0.0f;
  if (t < 64) {
    const int i = t;
    float acc = -sl[NH * NX + i];
#pragma unroll 4
    for (int k0 = 0; k0 < NX; k0 += 4)
      acc += dot4(ld4(Qfg + i * NX + k0), ld4(sx + NH * NX + k0));
    p_i = acc;
    dx_i = x0g[b * NX + i] - sx[i];
  }
  __syncthreads();

  for (int idx = t; idx < NX * NX / 4; idx += 1024) {
    const int k = idx >> 4, i4 = (idx & 15) * 4;
    const float4 a4 = ld4(Ag + k * NX + i4);
    sAT[(i4 + 0) * 68 + k] = a4.x;
    sAT[(i4 + 1) * 68 + k] = a4.y;
    sAT[(i4 + 2) * 68 + k] = a4.z;
    sAT[(i4 + 3) * 68 + k] = a4.w;
  }
  __syncthreads();

  if (t >= 64) return;   // wave 0 continues barrier-free

  const int i = t;
  const int j = t & 31;
  const int hh = t >> 5;

  for (int s = NH - 1; s >= 0; --s) {
    // relaxed poll; single acquire on success
    while (__hip_atomic_load(flags + s, __ATOMIC_RELAXED,
                             __HIP_MEMORY_SCOPE_AGENT) == 0)
      __builtin_amdgcn_s_sleep(4);
    (void)__hip_atomic_load(flags + s, __ATOMIC_ACQUIRE,
                            __HIP_MEMORY_SCOPE_AGENT);

    const float* Pr = gP + (s + 1) * NX * NX + i * NX;
    const float* xr = xres + s * NX;
    float w = p_i;
#pragma unroll
    for (int k0 = 0; k0 < NX; k0 += 16) {
      w += dot4(ld4(Pr + k0),      ld4(xr + k0));
      w += dot4(ld4(Pr + k0 + 4),  ld4(xr + k0 + 4));
      w += dot4(ld4(Pr + k0 + 8),  ld4(xr + k0 + 8));
      w += dot4(ld4(Pr + k0 + 12), ld4(xr + k0 + 12));
    }
    swv[i] = w;

    float qx = lxs[s * NX + i];
#pragma unroll
    for (int k0 = 0; k0 < NX; k0 += 16) {
      qx += dot4(ld4(sAT + i * 68 + k0),      ld4(swv + k0));
      qx += dot4(ld4(sAT + i * 68 + k0 + 4),  ld4(swv + k0 + 4));
      qx += dot4(ld4(sAT + i * 68 + k0 + 8),  ld4(swv + k0 + 8));
      qx += dot4(ld4(sAT + i * 68 + k0 + 12), ld4(swv + k0 + 12));
    }

    float qa = 0.0f;
    const int kb = hh * 32;
#pragma unroll 8
    for (int kk = 0; kk < 32; ++kk)
      qa = fmaf(Bg[(kb + kk) * NU + j], swv[kb + kk], qa);
    qa += __shfl_xor(qa, 32);
    const float qu = qa + lus[s * NU + j];
    if (hh == 0) sqv[j] = qu;

    const float* Qr = gQI + s * NU * NU + j * NU + hh * 16;
    float ka = dot4(ld4(Qr),      ld4(sqv + hh * 16))
             + dot4(ld4(Qr + 4),  ld4(sqv + hh * 16 + 4))
             + dot4(ld4(Qr + 8),  ld4(sqv + hh * 16 + 8))
             + dot4(ld4(Qr + 12), ld4(sqv + hh * 16 + 12));
    ka += __shfl_xor(ka, 32);
    if (hh == 0) kv[s * NU + j] = -ka;

    // p = qx + Qxu k   (gX x-major: lane i reads 32 contiguous floats)
    const float* Xs = gX + s * 2048 + i * 32;
    float pp = qx;
#pragma unroll
    for (int m0 = 0; m0 < NU; m0 += 4)
      pp += dot4(ld4(Xs + m0), ld4(kv + s * NU + m0));
    p_i = pp;
  }

  // flags[0] acquire above covers all gK stores (stage 0 is produced last)
  sdxv[i] = dx_i;
  for (int s = 0; s < NH; ++s) {
    const float* Kr = gK + s * NU * NX + j * NX + hh * 32;
    const float* dxh = sdxv + hh * 32;
    float da = 0.0f;
#pragma unroll
    for (int k0 = 0; k0 < 32; k0 += 16) {
      da += dot4(ld4(Kr + k0),      ld4(dxh + k0));
      da += dot4(ld4(Kr + k0 + 4),  ld4(dxh + k0 + 4));
      da += dot4(ld4(Kr + k0 + 8),  ld4(dxh + k0 + 8));
      da += dot4(ld4(Kr + k0 + 12), ld4(dxh + k0 + 12));
    }
    da += __shfl_xor(da, 32);
    const float du = da + kv[s * NU + j];
    if (hh == 0) {
      const int gi = (s * NB + b) * NU + j;
      outp[gi] = ug[gi] + du;
      sduv[j] = du;
    }

    float nxv = xres[s * NX + i];
    const float* Ar = Ag + i * NX;
#pragma unroll
    for (int k0 = 0; k0 < NX; k0 += 4)
      nxv += dot4(ld4(Ar + k0), ld4(sdxv + k0));
    const float* Br = Bg + i * NU;
#pragma unroll
    for (int m0 = 0; m0 < NU; m0 += 4)
      nxv += dot4(ld4(Br + m0), ld4(sduv + m0));
    sdxv[i] = nxv;
  }
}

__global__ void k_zero(float* ws) {
  if (threadIdx.x < 64) ((int*)(ws + WS_P))[threadIdx.x] = 0;
}

__global__ __launch_bounds__(1024) void k_fused(
    const float* __restrict__ x0g, const float* __restrict__ xg,
    const float* __restrict__ ug, const float* __restrict__ lg,
    const float* __restrict__ Ag, const float* __restrict__ Bg,
    const float* __restrict__ Qxg, const float* __restrict__ Rug,
    const float* __restrict__ Qfg, float* __restrict__ ws,
    float* __restrict__ outp) {
  __shared__ __align__(16) char smem[SMEMB];
  if (blockIdx.x == 0)
    producer(smem, Ag, Bg, Qxg, Rug, Qfg, ws);
  else
    consumer((float*)smem, blockIdx.x - 1, x0g, xg, ug, lg, Ag, Bg, Qxg, Rug,
             Qfg, ws, outp);
}

extern "C" void kernel_launch(void* const* d_in, const int* in_sizes, int n_in,
                              void* d_out, int out_size, void* d_ws, size_t ws_size,
                              hipStream_t stream) {
  const float* x0  = (const float*)d_in[0];
  const float* x   = (const float*)d_in[1];
  const float* u   = (const float*)d_in[2];
  const float* lmd = (const float*)d_in[3];
  const float* A   = (const float*)d_in[4];
  const float* Bm  = (const float*)d_in[5];
  const float* Qx  = (const float*)d_in[6];
  const float* Ru  = (const float*)d_in[7];
  const float* Qf  = (const float*)d_in[8];
  float* ws  = (float*)d_ws;
  float* out = (float*)d_out;

  hipLaunchKernelGGL(k_zero, dim3(1), dim3(64), 0, stream, ws);
  hipLaunchKernelGGL(k_fused, dim3(NB + 1), dim3(1024), 0, stream,
                     x0, x, u, lmd, A, Bm, Qx, Ru, Qf, ws, out);
}